// Round 1
// baseline (552.168 us; speedup 1.0000x reference)
//
#include <hip/hip_runtime.h>
#include <math.h>

#define T_LEN 4096
#define B_SZ  512

// ---------------------------------------------------------------------------
// emission: fl(fl(fl(-0.5*x)*x) - fl32(0.5*log(2*pi)))  -- exact op order,
// no FMA contraction.
__device__ __forceinline__ float emis(float xv) {
    float a = __fmul_rn(-0.5f, xv);
    float b = __fmul_rn(a, xv);
    return __fsub_rn(b, (float)0.9189385332046727);
}

// ---------------------------------------------------------------------------
// Pass 0: logA[i*16+j] = fl32(log64(trans[i][j])) - fl32(log64(rowsum_i))
// rowsum uses numpy's pairwise-16 tree. log_pi == logA row 0 (same ops).
__global__ void k_prep(const float* __restrict__ hmm, float* __restrict__ logA) {
    int tid = threadIdx.x;
    if (tid >= 256) return;
    int i = tid >> 4, j = tid & 15;
    const float* row = hmm + i * 16;
    float r[8];
#pragma unroll
    for (int k = 0; k < 8; ++k) r[k] = __fadd_rn(row[k], row[k + 8]);
    float s = __fadd_rn(
        __fadd_rn(__fadd_rn(r[0], r[1]), __fadd_rn(r[2], r[3])),
        __fadd_rn(__fadd_rn(r[4], r[5]), __fadd_rn(r[6], r[7])));
    float la = (float)log((double)row[j]);
    float ls = (float)log((double)s);
    logA[tid] = __fsub_rn(la, ls);
}

// ---------------------------------------------------------------------------
// Pass 1: serial delta-only forward. 16 lanes per batch, DPP row_ror exchange.
#define DPP_ROR_I(K, SRC) __builtin_amdgcn_update_dpp(0, (SRC), 0x120 + (K), 0xF, 0xF, false)
#define SCORE(K) __fadd_rn(__int_as_float(DPP_ROR_I(K, __float_as_int(d))), a[K])

#define VITERBI_STEP(XT, ROWIDX)                                                      \
    {                                                                                 \
        float s0 = __fadd_rn(d, a[0]);                                                \
        float s1 = SCORE(1);   float s2 = SCORE(2);   float s3 = SCORE(3);            \
        float s4 = SCORE(4);   float s5 = SCORE(5);   float s6 = SCORE(6);            \
        float s7 = SCORE(7);   float s8 = SCORE(8);   float s9 = SCORE(9);            \
        float s10 = SCORE(10); float s11 = SCORE(11); float s12 = SCORE(12);          \
        float s13 = SCORE(13); float s14 = SCORE(14); float s15 = SCORE(15);          \
        float m = fmaxf(                                                              \
            fmaxf(fmaxf(fmaxf(s0, s1), fmaxf(s2, s3)),                                \
                  fmaxf(fmaxf(s4, s5), fmaxf(s6, s7))),                               \
            fmaxf(fmaxf(fmaxf(s8, s9), fmaxf(s10, s11)),                              \
                  fmaxf(fmaxf(s12, s13), fmaxf(s14, s15))));                          \
        d = __fadd_rn(m, emis(XT));                                                   \
        dcol[(size_t)(ROWIDX) * 16] = d;                                              \
    }

__global__ __launch_bounds__(64) void k_fwd(const float* __restrict__ x,
                                            const float* __restrict__ logA,
                                            float* __restrict__ dchunk,
                                            float* __restrict__ carry,
                                            int ts, int te, int ROWS, int first) {
    const int lane = threadIdx.x;
    const int j = lane & 15;
    const int b = blockIdx.x * 4 + (lane >> 4);

    // Self-calibrating DPP direction: rotate the lane-id to learn which state's
    // delta lands in slot K, then load the matching A entry. a[K] = logA[sig][j].
    float a[16];
    {
        a[0] = logA[j * 16 + j];
#define LOADA(K) { int sk = DPP_ROR_I(K, j); a[K] = logA[sk * 16 + j]; }
        LOADA(1)  LOADA(2)  LOADA(3)  LOADA(4)  LOADA(5)
        LOADA(6)  LOADA(7)  LOADA(8)  LOADA(9)  LOADA(10)
        LOADA(11) LOADA(12) LOADA(13) LOADA(14) LOADA(15)
#undef LOADA
    }

    const float* xb = x + (size_t)b * T_LEN;
    float d;
    if (first) {
        // delta0 = fl(log_pi[j] + emit[b,0]); log_pi == logA row 0
        d = __fadd_rn(logA[j], emis(xb[0]));
    } else {
        d = carry[b * 16 + j];
    }
    float* dcol = dchunk + (size_t)b * ROWS * 16 + j;
    dcol[0] = d;  // row 0 = delta_ts

    // 16-deep rolling prefetch of x (clamped index; wasted loads harmless)
    float xq[16];
#pragma unroll
    for (int u = 0; u < 16; ++u) {
        int tp = ts + 1 + u; if (tp > T_LEN - 1) tp = T_LEN - 1;
        xq[u] = xb[tp];
    }

    int t = ts + 1;
    while (t + 15 <= te) {
#pragma unroll
        for (int u = 0; u < 16; ++u) {
            float xt = xq[u];
            int tp = t + u + 16; if (tp > T_LEN - 1) tp = T_LEN - 1;
            xq[u] = xb[tp];
            VITERBI_STEP(xt, t + u - ts)
        }
        t += 16;
    }
    for (; t <= te; ++t) {  // tail (<16 iters), direct loads
        float xt = xb[t];
        VITERBI_STEP(xt, t - ts)
    }
    carry[b * 16 + j] = d;
}

// ---------------------------------------------------------------------------
// Pass 2: psi_t[b][j] = argmax_i fl(delta_{t-1}[b][i] + logA[i][j]), first-wins.
// Fully parallel over (b, t). One thread per (b, t); coalesced along t.
__global__ __launch_bounds__(256) void k_psi(const float* __restrict__ dchunk,
                                             const float* __restrict__ logA,
                                             unsigned char* __restrict__ psi,
                                             int ts, int te, int ROWS) {
    __shared__ float AT[256];  // AT[j][i] = logA[i][j]
    int tid = threadIdx.x;
    AT[(tid & 15) * 16 + (tid >> 4)] = logA[tid];
    __syncthreads();
    int cl = te - ts;
    int tt = blockIdx.x * 256 + tid;
    if (tt >= cl) return;
    int b = blockIdx.y;
    const float4* dr = (const float4*)(dchunk + ((size_t)b * ROWS + tt) * 16);
    float4 q0 = dr[0], q1 = dr[1], q2 = dr[2], q3 = dr[3];
    float dd[16] = {q0.x, q0.y, q0.z, q0.w, q1.x, q1.y, q1.z, q1.w,
                    q2.x, q2.y, q2.z, q2.w, q3.x, q3.y, q3.z, q3.w};
    unsigned pk[4] = {0u, 0u, 0u, 0u};
#pragma unroll
    for (int jj = 0; jj < 16; ++jj) {
        float best = __fadd_rn(dd[0], AT[jj * 16 + 0]);
        int arg = 0;
#pragma unroll
        for (int i = 1; i < 16; ++i) {
            float s = __fadd_rn(dd[i], AT[jj * 16 + i]);
            if (s > best) arg = i;        // strict > keeps first max (np/jnp tie rule)
            best = fmaxf(best, s);
        }
        pk[jj >> 2] |= (unsigned)arg << ((jj & 3) * 8);
    }
    int t = ts + 1 + tt;
    *((uint4*)(psi + ((size_t)b * T_LEN + t) * 16)) = make_uint4(pk[0], pk[1], pk[2], pk[3]);
}

// ---------------------------------------------------------------------------
// Pass 3A: per-(b, 64-step chunk) composed backtrace maps. 16 lanes = 16 states.
__global__ __launch_bounds__(256) void k_maps(const unsigned char* __restrict__ psi,
                                              unsigned char* __restrict__ M) {
    int lane = threadIdx.x;
    int z = lane & 15;
    int g = blockIdx.x * 16 + (lane >> 4);  // g = b*64 + c
    int b = g >> 6, c = g & 63;
    int t_lo = c * 64;
    int t_hi = t_lo + 64; if (t_hi > T_LEN - 1) t_hi = T_LEN - 1;
    const unsigned char* pb = psi + (size_t)b * T_LEN * 16;
    int v = z;
    for (int t = t_hi; t > t_lo; --t) v = pb[t * 16 + v];
    M[(size_t)g * 16 + z] = (unsigned char)v;
}

// Pass 3B: zT = argmax(delta_final) (first-wins), then serial chunk-boundary states.
__global__ __launch_bounds__(256) void k_bound(const float* __restrict__ carry,
                                               const unsigned char* __restrict__ M,
                                               unsigned char* __restrict__ E,
                                               int* __restrict__ out) {
    int b = blockIdx.x * 256 + threadIdx.x;
    if (b >= B_SZ) return;
    const float* dT = carry + b * 16;
    float best = dT[0]; int zT = 0;
#pragma unroll
    for (int i = 1; i < 16; ++i) {
        float s = dT[i];
        if (s > best) zT = i;
        best = fmaxf(best, s);
    }
    out[(size_t)b * T_LEN + (T_LEN - 1)] = zT;
    int z = zT;
    for (int c = 63; c >= 0; --c) {
        E[b * 64 + c] = (unsigned char)z;   // state at t_hi(c)
        z = M[((size_t)b * 64 + c) * 16 + z];
    }
}

// Pass 3C: within-chunk walks, writes path[b][t] for t in [t_lo, t_hi).
__global__ __launch_bounds__(256) void k_walk(const unsigned char* __restrict__ psi,
                                              const unsigned char* __restrict__ E,
                                              int* __restrict__ out) {
    int idx = blockIdx.x * 256 + threadIdx.x;  // 32768 = 512*64
    int b = idx >> 6, c = idx & 63;
    int t_lo = c * 64;
    int t_hi = t_lo + 64; if (t_hi > T_LEN - 1) t_hi = T_LEN - 1;
    const unsigned char* pb = psi + (size_t)b * T_LEN * 16;
    int* ob = out + (size_t)b * T_LEN;
    int cur = E[b * 64 + c];
    for (int t = t_hi; t > t_lo; --t) {
        cur = pb[t * 16 + cur];
        ob[t - 1] = cur;
    }
}

// ---------------------------------------------------------------------------
extern "C" void kernel_launch(void* const* d_in, const int* in_sizes, int n_in,
                              void* d_out, int out_size, void* d_ws, size_t ws_size,
                              hipStream_t stream) {
    (void)in_sizes; (void)n_in; (void)out_size;
    const float* x   = (const float*)d_in[0];   // [512][4096] fp32
    const float* hmm = (const float*)d_in[1];   // [64][16][16] fp32 (only [0] used)
    int* out = (int*)d_out;                     // [512][4096] int32

    char* w = (char*)d_ws;
    float* logA  = (float*)w;                                  // 1KB (reserve 4KB)
    float* carry = (float*)(w + 4096);                         // 32KB
    unsigned char* psi = (unsigned char*)(w + 4096 + 32768);   // 33.55MB
    unsigned char* M   = psi + (size_t)B_SZ * T_LEN * 16;      // 512KB
    unsigned char* E   = M + (size_t)B_SZ * 64 * 16;           // 32KB
    float* dchunk = (float*)(E + (size_t)B_SZ * 64);           // rest: delta rows

    size_t fixed = 4096 + 32768 + (size_t)B_SZ * T_LEN * 16
                 + (size_t)B_SZ * 64 * 16 + (size_t)B_SZ * 64;
    size_t rem = (ws_size > fixed) ? (ws_size - fixed) : 0;
    long rows_cap = (long)(rem / ((size_t)B_SZ * 16 * 4));
    int ROWS = (rows_cap > T_LEN) ? T_LEN : (int)rows_cap;
    if (ROWS < 17) ROWS = 17;  // last-resort floor; assumes ws is at least ~34.2MB
    int CL = ROWS - 1;

    hipLaunchKernelGGL(k_prep, dim3(1), dim3(256), 0, stream, hmm, logA);

    int ts = 0;
    while (ts < T_LEN - 1) {
        int te = ts + CL; if (te > T_LEN - 1) te = T_LEN - 1;
        hipLaunchKernelGGL(k_fwd, dim3(128), dim3(64), 0, stream,
                           x, logA, dchunk, carry, ts, te, ROWS, (ts == 0) ? 1 : 0);
        int cl = te - ts;
        hipLaunchKernelGGL(k_psi, dim3((cl + 255) / 256, B_SZ), dim3(256), 0, stream,
                           dchunk, logA, psi, ts, te, ROWS);
        ts = te;
    }

    hipLaunchKernelGGL(k_maps,  dim3(2048), dim3(256), 0, stream, psi, M);
    hipLaunchKernelGGL(k_bound, dim3(2),    dim3(256), 0, stream, carry, M, E, out);
    hipLaunchKernelGGL(k_walk,  dim3(128),  dim3(256), 0, stream, psi, E, out);
}

// Round 2
// 456.235 us; speedup vs baseline: 1.2103x; 1.2103x over previous
//
#include <hip/hip_runtime.h>
#include <math.h>

#define T_LEN 4096
#define B_SZ  512
#define T_SPLIT 2048

// emission: fl(fl(fl(-0.5*x)*x) - fl32(0.5*log(2*pi)))
__device__ __forceinline__ float emis(float xv) {
    float a = __fmul_rn(-0.5f, xv);
    float b = __fmul_rn(a, xv);
    return __fsub_rn(b, (float)0.9189385332046727);
}

// ---------------------------------------------------------------------------
__global__ void k_prep(const float* __restrict__ hmm, float* __restrict__ logA) {
    int tid = threadIdx.x;
    if (tid >= 256) return;
    int i = tid >> 4, j = tid & 15;
    const float* row = hmm + i * 16;
    float r[8];
#pragma unroll
    for (int k = 0; k < 8; ++k) r[k] = __fadd_rn(row[k], row[k + 8]);
    float s = __fadd_rn(
        __fadd_rn(__fadd_rn(r[0], r[1]), __fadd_rn(r[2], r[3])),
        __fadd_rn(__fadd_rn(r[4], r[5]), __fadd_rn(r[6], r[7])));
    float la = (float)log((double)row[j]);
    float ls = (float)log((double)s);
    logA[tid] = __fsub_rn(la, ls);
}

// E[b][t] = emis(x[b][t]) — fully parallel, removes emission from serial loop.
__global__ __launch_bounds__(256) void k_emit(const float* __restrict__ x,
                                              float* __restrict__ E) {
    int i = blockIdx.x * 256 + threadIdx.x;  // 524288 threads x float4
    float4 v = ((const float4*)x)[i];
    float4 e;
    e.x = emis(v.x); e.y = emis(v.y); e.z = emis(v.z); e.w = emis(v.w);
    ((float4*)E)[i] = e;
}

// ---------------------------------------------------------------------------
#define DPP_ROR_I(K, SRC) __builtin_amdgcn_update_dpp(0, (SRC), 0x120 + (K), 0xF, 0xF, false)
#define M3(x, y, z) fmaxf(fmaxf(x, y), z)

// Variant A: 4 batches/wave, 16 lanes each, 15-DPP full source coverage.
#define SCOREA(K) __fadd_rn(__int_as_float(DPP_ROR_I(K, __float_as_int(d))), a[K])
#define STEPA(ET, ROWIDX)                                                             \
    {                                                                                 \
        float s0 = __fadd_rn(d, a[0]);                                                \
        float s1 = SCOREA(1);   float s2 = SCOREA(2);   float s3 = SCOREA(3);         \
        float s4 = SCOREA(4);   float s5 = SCOREA(5);   float s6 = SCOREA(6);         \
        float s7 = SCOREA(7);   float s8 = SCOREA(8);   float s9 = SCOREA(9);         \
        float s10 = SCOREA(10); float s11 = SCOREA(11); float s12 = SCOREA(12);       \
        float s13 = SCOREA(13); float s14 = SCOREA(14); float s15 = SCOREA(15);       \
        float u0 = M3(s0, s1, s2),  u1 = M3(s3, s4, s5),  u2 = M3(s6, s7, s8);        \
        float u3 = M3(s9, s10, s11), u4 = M3(s12, s13, s14);                          \
        float m = fmaxf(M3(u0, u1, u2), M3(u3, u4, s15));                             \
        d = __fadd_rn(m, ET);                                                         \
        dcol[(ROWIDX) * 16] = d;                                                      \
    }

__global__ __launch_bounds__(64) void k_fwdA(const float* __restrict__ E,
                                             const float* __restrict__ logA,
                                             float* __restrict__ dchunk,
                                             float* __restrict__ carry,
                                             int ts, int te, int first) {
    const int lane = threadIdx.x;
    const int j = lane & 15;
    const int b = blockIdx.x * 4 + (lane >> 4);
    float a[16];
    a[0] = logA[j * 16 + j];
#define LOADA(K) { int sk = DPP_ROR_I(K, j); a[K] = logA[sk * 16 + j]; }
    LOADA(1)  LOADA(2)  LOADA(3)  LOADA(4)  LOADA(5)
    LOADA(6)  LOADA(7)  LOADA(8)  LOADA(9)  LOADA(10)
    LOADA(11) LOADA(12) LOADA(13) LOADA(14) LOADA(15)
#undef LOADA
    const float* eb = E + b * T_LEN;
    float* dcol = dchunk + b * T_LEN * 16 + j;
    float d;
    if (first) { d = __fadd_rn(logA[j], eb[0]); dcol[0] = d; }
    else       { d = carry[b * 16 + j]; }

    float xq[16];
#pragma unroll
    for (int u = 0; u < 16; ++u) xq[u] = eb[ts + 1 + u];
    int t = ts + 1;
    while (t + 15 <= te) {
#pragma unroll
        for (int u = 0; u < 16; ++u) {
            float et = xq[u];
            xq[u] = eb[t + u + 16];   // padded E: overread safe, values unused
            STEPA(et, t + u)
        }
        t += 16;
    }
    for (; t <= te; ++t) { STEPA(eb[t], t) }
    carry[b * 16 + j] = d;
}

// ---------------------------------------------------------------------------
// Variant B: 2 batches/wave, 32 lanes/batch in 2 rows. Rows 1,3 hold delta
// pre-rotated by 8 (invariant via row-masked DPP). Row r covers 8 sources;
// cross-row combine via ds_swizzle xor-16. Max reassociation is exact.
#define SCOREB(K) \
    __fadd_rn(__int_as_float(__builtin_amdgcn_update_dpp(0, dR, 0x120 + (K), 0xF, 0xF, false)), a[K])
#define STEPB(ET, ROWIDX)                                                             \
    {                                                                                 \
        float s0f = __fadd_rn(__int_as_float(dR), a[0]);                              \
        float s1 = SCOREB(1); float s2 = SCOREB(2); float s3 = SCOREB(3);             \
        float s4 = SCOREB(4); float s5 = SCOREB(5); float s6 = SCOREB(6);             \
        float s7 = SCOREB(7);                                                         \
        float u0 = M3(s0f, s1, s2), u1 = M3(s3, s4, s5), u2 = fmaxf(s6, s7);          \
        float pm = M3(u0, u1, u2);                                                    \
        float om = __int_as_float(                                                    \
            __builtin_amdgcn_ds_swizzle(__float_as_int(pm), 0x401F));                 \
        float m = fmaxf(pm, om);                                                      \
        float dd = __fadd_rn(m, ET);                                                  \
        dcol[(ROWIDX) * 16] = dd;                                                     \
        dR = __builtin_amdgcn_update_dpp(__float_as_int(dd), __float_as_int(dd),      \
                                         0x128, 0xA, 0xF, false);                     \
        dfin = dd;                                                                    \
    }

__global__ __launch_bounds__(64) void k_fwdB(const float* __restrict__ E,
                                             const float* __restrict__ logA,
                                             float* __restrict__ dchunk,
                                             float* __restrict__ carry,
                                             int ts, int te) {
    const int lane = threadIdx.x;
    const int j = lane & 15;
    const int b = blockIdx.x * 2 + (lane >> 5);
    // Self-calibrated invariant state index: rows 1,3 = ror8(j), rows 0,2 = j.
    int s0 = __builtin_amdgcn_update_dpp(j, j, 0x128, 0xA, 0xF, false);
    float a[8];
    a[0] = logA[s0 * 16 + j];
#define LOADB(K) { int sk = DPP_ROR_I(K, s0); a[K] = logA[sk * 16 + j]; }
    LOADB(1) LOADB(2) LOADB(3) LOADB(4) LOADB(5) LOADB(6) LOADB(7)
#undef LOADB
    const float* eb = E + b * T_LEN;
    float* dcol = dchunk + b * T_LEN * 16 + j;
    float dal = carry[b * 16 + j];  // aligned delta at ts
    int dR = __builtin_amdgcn_update_dpp(__float_as_int(dal), __float_as_int(dal),
                                         0x128, 0xA, 0xF, false);
    float dfin = dal;

    float xq[16];
#pragma unroll
    for (int u = 0; u < 16; ++u) xq[u] = eb[ts + 1 + u];
    int t = ts + 1;
    while (t + 15 <= te) {
#pragma unroll
        for (int u = 0; u < 16; ++u) {
            float et = xq[u];
            xq[u] = eb[t + u + 16];   // overreads <= E[b*T+4096] (padded)
            STEPB(et, t + u)
        }
        t += 16;
    }
    for (; t <= te; ++t) { STEPB(eb[t], t) }
    carry[b * 16 + j] = dfin;
}

// ---------------------------------------------------------------------------
__global__ __launch_bounds__(256) void k_psi(const float* __restrict__ dchunk,
                                             const float* __restrict__ logA,
                                             unsigned char* __restrict__ psi,
                                             int ts, int te) {
    __shared__ float AT[256];  // AT[j][i] = logA[i][j]
    int tid = threadIdx.x;
    AT[(tid & 15) * 16 + (tid >> 4)] = logA[tid];
    __syncthreads();
    int cl = te - ts;
    int tt = blockIdx.x * 256 + tid;
    if (tt >= cl) return;
    int b = blockIdx.y;
    const float4* dr = (const float4*)(dchunk + ((size_t)b * T_LEN + tt) * 16);
    float4 q0 = dr[0], q1 = dr[1], q2 = dr[2], q3 = dr[3];
    float dd[16] = {q0.x, q0.y, q0.z, q0.w, q1.x, q1.y, q1.z, q1.w,
                    q2.x, q2.y, q2.z, q2.w, q3.x, q3.y, q3.z, q3.w};
    unsigned pk[4] = {0u, 0u, 0u, 0u};
#pragma unroll
    for (int jj = 0; jj < 16; ++jj) {
        float best = __fadd_rn(dd[0], AT[jj * 16 + 0]);
        int arg = 0;
#pragma unroll
        for (int i = 1; i < 16; ++i) {
            float s = __fadd_rn(dd[i], AT[jj * 16 + i]);
            if (s > best) arg = i;  // first-wins tie rule
            best = fmaxf(best, s);
        }
        pk[jj >> 2] |= (unsigned)arg << ((jj & 3) * 8);
    }
    int t = ts + 1 + tt;
    *((uint4*)(psi + ((size_t)b * T_LEN + t) * 16)) = make_uint4(pk[0], pk[1], pk[2], pk[3]);
}

// ---------------------------------------------------------------------------
__global__ __launch_bounds__(256) void k_maps(const unsigned char* __restrict__ psi,
                                              unsigned char* __restrict__ M) {
    int lane = threadIdx.x;
    int z = lane & 15;
    int g = blockIdx.x * 16 + (lane >> 4);
    int b = g >> 6, c = g & 63;
    int t_lo = c * 64;
    int t_hi = t_lo + 64; if (t_hi > T_LEN - 1) t_hi = T_LEN - 1;
    const unsigned char* pb = psi + (size_t)b * T_LEN * 16;
    int v = z;
    for (int t = t_hi; t > t_lo; --t) v = pb[t * 16 + v];
    M[(size_t)g * 16 + z] = (unsigned char)v;
}

__global__ __launch_bounds__(256) void k_bound(const float* __restrict__ carry,
                                               const unsigned char* __restrict__ M,
                                               unsigned char* __restrict__ E,
                                               int* __restrict__ out) {
    int b = blockIdx.x * 256 + threadIdx.x;
    if (b >= B_SZ) return;
    const float* dT = carry + b * 16;
    float best = dT[0]; int zT = 0;
#pragma unroll
    for (int i = 1; i < 16; ++i) {
        float s = dT[i];
        if (s > best) zT = i;
        best = fmaxf(best, s);
    }
    out[(size_t)b * T_LEN + (T_LEN - 1)] = zT;
    int z = zT;
    for (int c = 63; c >= 0; --c) {
        E[b * 64 + c] = (unsigned char)z;
        z = M[((size_t)b * 64 + c) * 16 + z];
    }
}

__global__ __launch_bounds__(256) void k_walk(const unsigned char* __restrict__ psi,
                                              const unsigned char* __restrict__ E,
                                              int* __restrict__ out) {
    int idx = blockIdx.x * 256 + threadIdx.x;  // 32768 = 512*64
    int b = idx >> 6, c = idx & 63;
    int t_lo = c * 64;
    int t_hi = t_lo + 64; if (t_hi > T_LEN - 1) t_hi = T_LEN - 1;
    const unsigned char* pb = psi + (size_t)b * T_LEN * 16;
    int* ob = out + (size_t)b * T_LEN;
    int cur = E[b * 64 + c];
    for (int t = t_hi; t > t_lo; --t) {
        cur = pb[t * 16 + cur];
        ob[t - 1] = cur;
    }
}

// ---------------------------------------------------------------------------
extern "C" void kernel_launch(void* const* d_in, const int* in_sizes, int n_in,
                              void* d_out, int out_size, void* d_ws, size_t ws_size,
                              hipStream_t stream) {
    (void)in_sizes; (void)n_in; (void)out_size; (void)ws_size;
    const float* x   = (const float*)d_in[0];   // [512][4096] fp32
    const float* hmm = (const float*)d_in[1];   // [64][16][16] fp32 (only [0] used)
    int* out = (int*)d_out;                     // [512][4096] int32

    char* w = (char*)d_ws;
    float* logA  = (float*)w;                                  // 4KB slot
    float* carry = (float*)(w + 4096);                         // 32KB
    unsigned char* psi = (unsigned char*)(w + 4096 + 32768);   // 33.55MB
    unsigned char* M   = psi + (size_t)B_SZ * T_LEN * 16;      // 512KB
    unsigned char* Eb  = M + (size_t)B_SZ * 64 * 16;           // 32KB (boundary states)
    float* dchunk = (float*)(Eb + (size_t)B_SZ * 64);          // 134.2MB deltas
    // Emission buffer aliases psi (8.4MB + pad < 33.5MB); E consumed by
    // k_fwdA/B before k_psi overwrites the region.
    float* Em = (float*)psi;

    hipLaunchKernelGGL(k_prep, dim3(1), dim3(256), 0, stream, hmm, logA);
    hipLaunchKernelGGL(k_emit, dim3((B_SZ * T_LEN / 4) / 256), dim3(256), 0, stream, x, Em);

    hipLaunchKernelGGL(k_fwdA, dim3(B_SZ / 4), dim3(64), 0, stream,
                       Em, logA, dchunk, carry, 0, T_SPLIT, 1);
    hipLaunchKernelGGL(k_fwdB, dim3(B_SZ / 2), dim3(64), 0, stream,
                       Em, logA, dchunk, carry, T_SPLIT, T_LEN - 1);

    hipLaunchKernelGGL(k_psi, dim3((T_LEN - 1 + 255) / 256, B_SZ), dim3(256), 0, stream,
                       dchunk, logA, psi, 0, T_LEN - 1);

    hipLaunchKernelGGL(k_maps,  dim3(2048), dim3(256), 0, stream, psi, M);
    hipLaunchKernelGGL(k_bound, dim3(2),    dim3(256), 0, stream, carry, M, Eb, out);
    hipLaunchKernelGGL(k_walk,  dim3(128),  dim3(256), 0, stream, psi, Eb, out);
}

// Round 3
// 449.049 us; speedup vs baseline: 1.2296x; 1.0160x over previous
//
#include <hip/hip_runtime.h>
#include <math.h>

#define T_LEN 4096
#define B_SZ  512

// emission: fl(fl(fl(-0.5*x)*x) - fl32(0.5*log(2*pi)))
__device__ __forceinline__ float emis(float xv) {
    float a = __fmul_rn(-0.5f, xv);
    float b = __fmul_rn(a, xv);
    return __fsub_rn(b, (float)0.9189385332046727);
}

// ---------------------------------------------------------------------------
__global__ void k_prep(const float* __restrict__ hmm, float* __restrict__ logA) {
    int tid = threadIdx.x;
    if (tid >= 256) return;
    int i = tid >> 4, j = tid & 15;
    const float* row = hmm + i * 16;
    float r[8];
#pragma unroll
    for (int k = 0; k < 8; ++k) r[k] = __fadd_rn(row[k], row[k + 8]);
    float s = __fadd_rn(
        __fadd_rn(__fadd_rn(r[0], r[1]), __fadd_rn(r[2], r[3])),
        __fadd_rn(__fadd_rn(r[4], r[5]), __fadd_rn(r[6], r[7])));
    float la = (float)log((double)row[j]);
    float ls = (float)log((double)s);
    logA[tid] = __fsub_rn(la, ls);
}

__global__ __launch_bounds__(256) void k_emit(const float* __restrict__ x,
                                              float* __restrict__ E) {
    int i = blockIdx.x * 256 + threadIdx.x;
    float4 v = ((const float4*)x)[i];
    float4 e;
    e.x = emis(v.x); e.y = emis(v.y); e.z = emis(v.z); e.w = emis(v.w);
    ((float4*)E)[i] = e;
}

// ---------------------------------------------------------------------------
// Forward: 2 batches/wave, 32 lanes/batch in 2 rows of 16. Rows 1,3 hold
// delta pre-rotated by 8 (invariant). Row r covers 8 sources via mov_dpp
// row_ror (single-instr DPP, no tied-old mov); cross-row combine via one
// ds_swizzle xor-16. Max reassociation is rounding-free => bit-exact.
#define DPP_ROR0(K, SRC) __builtin_amdgcn_update_dpp(0, (SRC), 0x120 + (K), 0xF, 0xF, false)
#define ROR(K, SRC)      __builtin_amdgcn_mov_dpp((SRC), 0x120 + (K), 0xF, 0xF, true)
#define M3(x, y, z) fmaxf(fmaxf(x, y), z)
#define SCOREB(K) __fadd_rn(__int_as_float(ROR(K, dR)), a[K])

#define STEPB(ET, ROWIDX)                                                             \
    {                                                                                 \
        float s0f = __fadd_rn(__int_as_float(dR), a[0]);                              \
        float s1 = SCOREB(1); float s2 = SCOREB(2); float s3 = SCOREB(3);             \
        float s4 = SCOREB(4); float s5 = SCOREB(5); float s6 = SCOREB(6);             \
        float s7 = SCOREB(7);                                                         \
        float pm = M3(M3(s0f, s1, s2), M3(s3, s4, s5), fmaxf(s6, s7));                \
        float om = __int_as_float(                                                    \
            __builtin_amdgcn_ds_swizzle(__float_as_int(pm), 0x401F));                 \
        float m = fmaxf(pm, om);                                                      \
        float dd = __fadd_rn(m, ET);                                                  \
        dcol[(ROWIDX) * 16] = dd;                                                     \
        dR = __builtin_amdgcn_update_dpp(__float_as_int(dd), __float_as_int(dd),      \
                                         0x128, 0xA, 0xF, false);                     \
        dfin = dd;                                                                    \
    }

__global__ __launch_bounds__(64) void k_fwd(const float* __restrict__ E,
                                            const float* __restrict__ logA,
                                            float* __restrict__ dchunk,
                                            float* __restrict__ carry) {
    const int lane = threadIdx.x;
    const int j = lane & 15;
    const int b = blockIdx.x * 2 + (lane >> 5);
    // Invariant source index: rows 1,3 = ror8(j), rows 0,2 = j (self-calibrated).
    int s0 = __builtin_amdgcn_update_dpp(j, j, 0x128, 0xA, 0xF, false);
    float a[8];
    a[0] = logA[s0 * 16 + j];
#define LOADB(K) { int sk = DPP_ROR0(K, s0); a[K] = logA[sk * 16 + j]; }
    LOADB(1) LOADB(2) LOADB(3) LOADB(4) LOADB(5) LOADB(6) LOADB(7)
#undef LOADB
    const float* eb = E + b * T_LEN;
    float* dcol = dchunk + b * T_LEN * 16 + j;

    // t = 0: delta0 = fl(log_pi[j] + E[b][0]); log_pi == logA row 0.
    float dal = __fadd_rn(logA[j], eb[0]);
    dcol[0] = dal;
    int dR = __builtin_amdgcn_update_dpp(__float_as_int(dal), __float_as_int(dal),
                                         0x128, 0xA, 0xF, false);
    float dfin = dal;

    // Steps 1..3 scalar (get t 4-aligned for float4 E loads).
    int t = 1;
    for (; t < 4; ++t) { STEPB(eb[t], t) }

    // Main: 16-step blocks, E prefetched as float4 (refill right after use;
    // prefetch distance 12-15 steps ~ >1000 cyc). Overreads stay in ws.
    float4 q0 = *(const float4*)(eb + t);
    float4 q1 = *(const float4*)(eb + t + 4);
    float4 q2 = *(const float4*)(eb + t + 8);
    float4 q3 = *(const float4*)(eb + t + 12);
    while (t + 15 <= T_LEN - 1) {
        STEPB(q0.x, t) STEPB(q0.y, t + 1) STEPB(q0.z, t + 2) STEPB(q0.w, t + 3)
        q0 = *(const float4*)(eb + t + 16);
        STEPB(q1.x, t + 4) STEPB(q1.y, t + 5) STEPB(q1.z, t + 6) STEPB(q1.w, t + 7)
        q1 = *(const float4*)(eb + t + 20);
        STEPB(q2.x, t + 8) STEPB(q2.y, t + 9) STEPB(q2.z, t + 10) STEPB(q2.w, t + 11)
        q2 = *(const float4*)(eb + t + 24);
        STEPB(q3.x, t + 12) STEPB(q3.y, t + 13) STEPB(q3.z, t + 14) STEPB(q3.w, t + 15)
        q3 = *(const float4*)(eb + t + 28);
        t += 16;
    }
    for (; t <= T_LEN - 1; ++t) { STEPB(eb[t], t) }
    carry[b * 16 + j] = dfin;
}

// ---------------------------------------------------------------------------
__global__ __launch_bounds__(256) void k_psi(const float* __restrict__ dchunk,
                                             const float* __restrict__ logA,
                                             unsigned char* __restrict__ psi) {
    __shared__ float AT[256];  // AT[j][i] = logA[i][j]
    int tid = threadIdx.x;
    AT[(tid & 15) * 16 + (tid >> 4)] = logA[tid];
    __syncthreads();
    int tt = blockIdx.x * 256 + tid;
    if (tt >= T_LEN - 1) return;
    int b = blockIdx.y;
    const float4* dr = (const float4*)(dchunk + ((size_t)b * T_LEN + tt) * 16);
    float4 q0 = dr[0], q1 = dr[1], q2 = dr[2], q3 = dr[3];
    float dd[16] = {q0.x, q0.y, q0.z, q0.w, q1.x, q1.y, q1.z, q1.w,
                    q2.x, q2.y, q2.z, q2.w, q3.x, q3.y, q3.z, q3.w};
    unsigned pk[4] = {0u, 0u, 0u, 0u};
#pragma unroll
    for (int jj = 0; jj < 16; ++jj) {
        float best = __fadd_rn(dd[0], AT[jj * 16 + 0]);
        int arg = 0;
#pragma unroll
        for (int i = 1; i < 16; ++i) {
            float s = __fadd_rn(dd[i], AT[jj * 16 + i]);
            if (s > best) arg = i;  // first-wins tie rule
            best = fmaxf(best, s);
        }
        pk[jj >> 2] |= (unsigned)arg << ((jj & 3) * 8);
    }
    int t = 1 + tt;
    *((uint4*)(psi + ((size_t)b * T_LEN + t) * 16)) = make_uint4(pk[0], pk[1], pk[2], pk[3]);
}

// ---------------------------------------------------------------------------
__global__ __launch_bounds__(256) void k_maps(const unsigned char* __restrict__ psi,
                                              unsigned char* __restrict__ M) {
    int lane = threadIdx.x;
    int z = lane & 15;
    int g = blockIdx.x * 16 + (lane >> 4);
    int b = g >> 6, c = g & 63;
    int t_lo = c * 64;
    int t_hi = t_lo + 64; if (t_hi > T_LEN - 1) t_hi = T_LEN - 1;
    const unsigned char* pb = psi + (size_t)b * T_LEN * 16;
    int v = z;
    for (int t = t_hi; t > t_lo; --t) v = pb[t * 16 + v];
    M[(size_t)g * 16 + z] = (unsigned char)v;
}

__global__ __launch_bounds__(256) void k_bound(const float* __restrict__ carry,
                                               const unsigned char* __restrict__ M,
                                               unsigned char* __restrict__ E,
                                               int* __restrict__ out) {
    int b = blockIdx.x * 256 + threadIdx.x;
    if (b >= B_SZ) return;
    const float* dT = carry + b * 16;
    float best = dT[0]; int zT = 0;
#pragma unroll
    for (int i = 1; i < 16; ++i) {
        float s = dT[i];
        if (s > best) zT = i;
        best = fmaxf(best, s);
    }
    out[(size_t)b * T_LEN + (T_LEN - 1)] = zT;
    int z = zT;
    for (int c = 63; c >= 0; --c) {
        E[b * 64 + c] = (unsigned char)z;
        z = M[((size_t)b * 64 + c) * 16 + z];
    }
}

__global__ __launch_bounds__(256) void k_walk(const unsigned char* __restrict__ psi,
                                              const unsigned char* __restrict__ E,
                                              int* __restrict__ out) {
    int idx = blockIdx.x * 256 + threadIdx.x;  // 32768 = 512*64
    int b = idx >> 6, c = idx & 63;
    int t_lo = c * 64;
    int t_hi = t_lo + 64; if (t_hi > T_LEN - 1) t_hi = T_LEN - 1;
    const unsigned char* pb = psi + (size_t)b * T_LEN * 16;
    int* ob = out + (size_t)b * T_LEN;
    int cur = E[b * 64 + c];
    for (int t = t_hi; t > t_lo; --t) {
        cur = pb[t * 16 + cur];
        ob[t - 1] = cur;
    }
}

// ---------------------------------------------------------------------------
extern "C" void kernel_launch(void* const* d_in, const int* in_sizes, int n_in,
                              void* d_out, int out_size, void* d_ws, size_t ws_size,
                              hipStream_t stream) {
    (void)in_sizes; (void)n_in; (void)out_size; (void)ws_size;
    const float* x   = (const float*)d_in[0];   // [512][4096] fp32
    const float* hmm = (const float*)d_in[1];   // [64][16][16] fp32 (only [0] used)
    int* out = (int*)d_out;                     // [512][4096] int32

    char* w = (char*)d_ws;
    float* logA  = (float*)w;                                  // 4KB slot
    float* carry = (float*)(w + 4096);                         // 32KB
    unsigned char* psi = (unsigned char*)(w + 4096 + 32768);   // 33.55MB
    unsigned char* M   = psi + (size_t)B_SZ * T_LEN * 16;      // 512KB
    unsigned char* Eb  = M + (size_t)B_SZ * 64 * 16;           // 32KB
    float* dchunk = (float*)(Eb + (size_t)B_SZ * 64);          // 134.2MB deltas
    float* Em = (float*)psi;  // emission aliases psi region (consumed pre-k_psi)

    hipLaunchKernelGGL(k_prep, dim3(1), dim3(256), 0, stream, hmm, logA);
    hipLaunchKernelGGL(k_emit, dim3((B_SZ * T_LEN / 4) / 256), dim3(256), 0, stream, x, Em);

    hipLaunchKernelGGL(k_fwd, dim3(B_SZ / 2), dim3(64), 0, stream,
                       Em, logA, dchunk, carry);

    hipLaunchKernelGGL(k_psi, dim3((T_LEN - 1 + 255) / 256, B_SZ), dim3(256), 0, stream,
                       dchunk, logA, psi);

    hipLaunchKernelGGL(k_maps,  dim3(2048), dim3(256), 0, stream, psi, M);
    hipLaunchKernelGGL(k_bound, dim3(2),    dim3(256), 0, stream, carry, M, Eb, out);
    hipLaunchKernelGGL(k_walk,  dim3(128),  dim3(256), 0, stream, psi, Eb, out);
}

// Round 4
// 387.496 us; speedup vs baseline: 1.4250x; 1.1588x over previous
//
#include <hip/hip_runtime.h>
#include <math.h>

#define T_LEN 4096
#define B_SZ  512

// emission: fl(fl(fl(-0.5*x)*x) - fl32(0.5*log(2*pi)))
__device__ __forceinline__ float emis(float xv) {
    float a = __fmul_rn(-0.5f, xv);
    float b = __fmul_rn(a, xv);
    return __fsub_rn(b, (float)0.9189385332046727);
}

// ---------------------------------------------------------------------------
// logA[i*16+j] = fl32(log64(trans[i][j])) - fl32(log64(rowsum_i)), numpy
// pairwise-16 rowsum. Also writes logAT (transposed) for k_psi scalar loads.
__global__ void k_prep(const float* __restrict__ hmm, float* __restrict__ logA,
                       float* __restrict__ logAT) {
    int tid = threadIdx.x;
    if (tid >= 256) return;
    int i = tid >> 4, j = tid & 15;
    const float* row = hmm + i * 16;
    float r[8];
#pragma unroll
    for (int k = 0; k < 8; ++k) r[k] = __fadd_rn(row[k], row[k + 8]);
    float s = __fadd_rn(
        __fadd_rn(__fadd_rn(r[0], r[1]), __fadd_rn(r[2], r[3])),
        __fadd_rn(__fadd_rn(r[4], r[5]), __fadd_rn(r[6], r[7])));
    float la = (float)log((double)row[j]);
    float ls = (float)log((double)s);
    float v = __fsub_rn(la, ls);
    logA[tid] = v;
    logAT[j * 16 + i] = v;
}

__global__ __launch_bounds__(256) void k_emit(const float* __restrict__ x,
                                              float* __restrict__ E) {
    int i = blockIdx.x * 256 + threadIdx.x;
    float4 v = ((const float4*)x)[i];
    float4 e;
    e.x = emis(v.x); e.y = emis(v.y); e.z = emis(v.z); e.w = emis(v.w);
    ((float4*)E)[i] = e;
}

// ---------------------------------------------------------------------------
// Forward: 4 batches/wave, 16 lanes/batch. Rotation fused into the score add
// via inline-asm v_add_f32_dpp (1 slot per source instead of mov_dpp+add).
// a[] mapping self-calibrated with the identical row_ror ctrl (r1-proven).
#define DPP_ROR0(K, SRC) __builtin_amdgcn_update_dpp(0, (SRC), 0x120 + (K), 0xF, 0xF, false)
#define M3(x, y, z) fmaxf(fmaxf(x, y), z)

#define ADDPP(DST, K)                                                                 \
    asm("v_add_f32_dpp %0, %1, %2 row_ror:" #K " row_mask:0xf bank_mask:0xf"          \
        : "=v"(DST) : "v"(d), "v"(a[K]))

#define STEPA(ET, ROWIDX)                                                             \
    {                                                                                 \
        float s0 = __fadd_rn(d, a[0]);                                                \
        float s1, s2, s3, s4, s5, s6, s7, s8, s9, s10, s11, s12, s13, s14, s15;       \
        ADDPP(s1, 1);   ADDPP(s2, 2);   ADDPP(s3, 3);   ADDPP(s4, 4);                 \
        ADDPP(s5, 5);   ADDPP(s6, 6);   ADDPP(s7, 7);   ADDPP(s8, 8);                 \
        ADDPP(s9, 9);   ADDPP(s10, 10); ADDPP(s11, 11); ADDPP(s12, 12);               \
        ADDPP(s13, 13); ADDPP(s14, 14); ADDPP(s15, 15);                               \
        float u0 = M3(s0, s1, s2),  u1 = M3(s3, s4, s5),  u2 = M3(s6, s7, s8);        \
        float u3 = M3(s9, s10, s11), u4 = M3(s12, s13, s14);                          \
        float m = fmaxf(M3(u0, u1, u2), M3(u3, u4, s15));                             \
        d = __fadd_rn(m, ET);                                                         \
        dcol[(ROWIDX) * 16] = d;                                                      \
    }

__global__ __launch_bounds__(64) void k_fwd(const float* __restrict__ E,
                                            const float* __restrict__ logA,
                                            float* __restrict__ dchunk,
                                            float* __restrict__ carry) {
    const int lane = threadIdx.x;
    const int j = lane & 15;
    const int b = blockIdx.x * 4 + (lane >> 4);
    float a[16];
    a[0] = logA[j * 16 + j];
#define LOADA(K) { int sk = DPP_ROR0(K, j); a[K] = logA[sk * 16 + j]; }
    LOADA(1)  LOADA(2)  LOADA(3)  LOADA(4)  LOADA(5)
    LOADA(6)  LOADA(7)  LOADA(8)  LOADA(9)  LOADA(10)
    LOADA(11) LOADA(12) LOADA(13) LOADA(14) LOADA(15)
#undef LOADA
    const float* eb = E + b * T_LEN;
    float* dcol = dchunk + b * T_LEN * 16 + j;

    // t = 0: delta0 = fl(log_pi[j] + E[b][0]); log_pi == logA row 0.
    float d = __fadd_rn(logA[j], eb[0]);
    dcol[0] = d;

    // steps 1..3 scalar to 4-align t for float4 E loads
    int t = 1;
    for (; t < 4; ++t) { STEPA(eb[t], t) }

    float4 q0 = *(const float4*)(eb + t);
    float4 q1 = *(const float4*)(eb + t + 4);
    float4 q2 = *(const float4*)(eb + t + 8);
    float4 q3 = *(const float4*)(eb + t + 12);
    while (t + 15 <= T_LEN - 1) {
        STEPA(q0.x, t) STEPA(q0.y, t + 1) STEPA(q0.z, t + 2) STEPA(q0.w, t + 3)
        q0 = *(const float4*)(eb + t + 16);
        STEPA(q1.x, t + 4) STEPA(q1.y, t + 5) STEPA(q1.z, t + 6) STEPA(q1.w, t + 7)
        q1 = *(const float4*)(eb + t + 20);
        STEPA(q2.x, t + 8) STEPA(q2.y, t + 9) STEPA(q2.z, t + 10) STEPA(q2.w, t + 11)
        q2 = *(const float4*)(eb + t + 24);
        STEPA(q3.x, t + 12) STEPA(q3.y, t + 13) STEPA(q3.z, t + 14) STEPA(q3.w, t + 15)
        q3 = *(const float4*)(eb + t + 28);
        t += 16;
    }
    for (; t <= T_LEN - 1; ++t) { STEPA(eb[t], t) }
    carry[b * 16 + j] = d;
}

// ---------------------------------------------------------------------------
// psi: one thread per (b,t). AT columns read through the SCALAR path (logAT
// address is wave-uniform; jj loop not unrolled) -> zero LDS traffic.
__global__ __launch_bounds__(256) void k_psi(const float* __restrict__ dchunk,
                                             const float* __restrict__ logAT,
                                             unsigned char* __restrict__ psi) {
    int tt = blockIdx.x * 256 + threadIdx.x;
    if (tt >= T_LEN - 1) return;
    int b = blockIdx.y;
    const float4* dr = (const float4*)(dchunk + ((size_t)b * T_LEN + tt) * 16);
    float4 v0 = dr[0], v1 = dr[1], v2 = dr[2], v3 = dr[3];
    float dd[16] = {v0.x, v0.y, v0.z, v0.w, v1.x, v1.y, v1.z, v1.w,
                    v2.x, v2.y, v2.z, v2.w, v3.x, v3.y, v3.z, v3.w};
    unsigned long long pk = 0ull;
#pragma clang loop unroll(disable)
    for (int jj = 0; jj < 16; ++jj) {
        const float* col = logAT + (jj << 4);   // wave-uniform -> s_load
        float best = __fadd_rn(dd[0], col[0]);
        int arg = 0;
#pragma unroll
        for (int i = 1; i < 16; ++i) {
            float s = __fadd_rn(dd[i], col[i]);
            if (s > best) arg = i;  // first-wins tie rule (i ascending)
            best = fmaxf(best, s);
        }
        pk |= (unsigned long long)arg << (jj * 4);
    }
    // expand 16 nibbles -> 16 bytes
    unsigned w[4];
#pragma unroll
    for (int q = 0; q < 4; ++q) {
        unsigned h = (unsigned)(pk >> (16 * q)) & 0xFFFFu;
        w[q] = (h & 0xFu) | ((h & 0xF0u) << 4) | ((h & 0xF00u) << 8) | ((h & 0xF000u) << 12);
    }
    int t = 1 + tt;
    *((uint4*)(psi + ((size_t)b * T_LEN + t) * 16)) = make_uint4(w[0], w[1], w[2], w[3]);
}

// ---------------------------------------------------------------------------
// maps: per-(b,c) composed backtrace over a 64-step chunk, psi staged in LDS.
__global__ __launch_bounds__(256) void k_maps(const unsigned char* __restrict__ psi,
                                              unsigned char* __restrict__ M) {
    __shared__ unsigned char buf[16][1024];
    int tid = threadIdx.x;
    int grp = tid >> 4, lane = tid & 15;
    int g = blockIdx.x * 16 + grp;  // g = b*64 + c
    int b = g >> 6, c = g & 63;
    int t_lo = c * 64;
    int t_hi = t_lo + 64; if (t_hi > T_LEN - 1) t_hi = T_LEN - 1;
    int n16 = t_hi - t_lo;  // rows of 16B to stage (t in (t_lo, t_hi])
    const uint4* src = (const uint4*)(psi + ((size_t)b * T_LEN + t_lo + 1) * 16);
    uint4* dst = (uint4*)buf[grp];
    for (int r = lane; r < n16; r += 16) dst[r] = src[r];
    __syncthreads();
    int v = lane;
    for (int t = t_hi; t > t_lo; --t) v = buf[grp][(t - t_lo - 1) * 16 + v];
    M[(size_t)g * 16 + lane] = (unsigned char)v;
}

__global__ __launch_bounds__(256) void k_bound(const float* __restrict__ carry,
                                               const unsigned char* __restrict__ M,
                                               unsigned char* __restrict__ Eb,
                                               int* __restrict__ out) {
    int b = blockIdx.x * 256 + threadIdx.x;
    if (b >= B_SZ) return;
    const float* dT = carry + b * 16;
    float best = dT[0]; int zT = 0;
#pragma unroll
    for (int i = 1; i < 16; ++i) {
        float s = dT[i];
        if (s > best) zT = i;
        best = fmaxf(best, s);
    }
    out[(size_t)b * T_LEN + (T_LEN - 1)] = zT;
    int z = zT;
    for (int c = 63; c >= 0; --c) {
        Eb[b * 64 + c] = (unsigned char)z;
        z = M[((size_t)b * 64 + c) * 16 + z];
    }
}

// walk: stage chunk psi in LDS (16 lanes), lane 0 walks + writes path ints.
__global__ __launch_bounds__(256) void k_walk(const unsigned char* __restrict__ psi,
                                              const unsigned char* __restrict__ Eb,
                                              int* __restrict__ out) {
    __shared__ unsigned char buf[16][1024];
    int tid = threadIdx.x;
    int grp = tid >> 4, lane = tid & 15;
    int g = blockIdx.x * 16 + grp;  // g = b*64 + c
    int b = g >> 6, c = g & 63;
    int t_lo = c * 64;
    int t_hi = t_lo + 64; if (t_hi > T_LEN - 1) t_hi = T_LEN - 1;
    int n16 = t_hi - t_lo;
    const uint4* src = (const uint4*)(psi + ((size_t)b * T_LEN + t_lo + 1) * 16);
    uint4* dst = (uint4*)buf[grp];
    for (int r = lane; r < n16; r += 16) dst[r] = src[r];
    __syncthreads();
    if (lane == 0) {
        int cur = Eb[b * 64 + c];
        int* ob = out + (size_t)b * T_LEN;
        for (int t = t_hi; t > t_lo; --t) {
            cur = buf[grp][(t - t_lo - 1) * 16 + cur];
            ob[t - 1] = cur;
        }
    }
}

// ---------------------------------------------------------------------------
extern "C" void kernel_launch(void* const* d_in, const int* in_sizes, int n_in,
                              void* d_out, int out_size, void* d_ws, size_t ws_size,
                              hipStream_t stream) {
    (void)in_sizes; (void)n_in; (void)out_size; (void)ws_size;
    const float* x   = (const float*)d_in[0];   // [512][4096] fp32
    const float* hmm = (const float*)d_in[1];   // [64][16][16] fp32 (only [0] used)
    int* out = (int*)d_out;                     // [512][4096] int32

    char* w = (char*)d_ws;
    float* logA  = (float*)w;                                  // 1KB
    float* logAT = (float*)(w + 1024);                         // 1KB (4KB slot)
    float* carry = (float*)(w + 4096);                         // 32KB
    unsigned char* psi = (unsigned char*)(w + 4096 + 32768);   // 33.55MB
    unsigned char* M   = psi + (size_t)B_SZ * T_LEN * 16;      // 512KB
    unsigned char* Eb  = M + (size_t)B_SZ * 64 * 16;           // 32KB
    float* dchunk = (float*)(Eb + (size_t)B_SZ * 64);          // 134.2MB
    float* Em = (float*)psi;  // emissions alias psi region (consumed pre-k_psi)

    hipLaunchKernelGGL(k_prep, dim3(1), dim3(256), 0, stream, hmm, logA, logAT);
    hipLaunchKernelGGL(k_emit, dim3((B_SZ * T_LEN / 4) / 256), dim3(256), 0, stream, x, Em);

    hipLaunchKernelGGL(k_fwd, dim3(B_SZ / 4), dim3(64), 0, stream,
                       Em, logA, dchunk, carry);

    hipLaunchKernelGGL(k_psi, dim3((T_LEN - 1 + 255) / 256, B_SZ), dim3(256), 0, stream,
                       dchunk, logAT, psi);

    hipLaunchKernelGGL(k_maps,  dim3(2048), dim3(256), 0, stream, psi, M);
    hipLaunchKernelGGL(k_bound, dim3(2),    dim3(256), 0, stream, carry, M, Eb, out);
    hipLaunchKernelGGL(k_walk,  dim3(2048), dim3(256), 0, stream, psi, Eb, out);
}